// Round 2
// baseline (10571.229 us; speedup 1.0000x reference)
//
#include <hip/hip_runtime.h>

// PressureProjection on MI355X — round 2.
// Changes vs R1 (atomic-bound at 24M memory-side atomics; uncoalesced CSR rows):
//  * hist kernel: ONLY cnt[dst]++ (8M atomics, was 24M incl. float accums)
//  * diag/div computed atomic-free as CSR row sums in node_setup
//  * scatter carries (src,w) and (eid,flux) as 8B int2 stores
//  * matvec / node_setup / finalize: 16 lanes per CSR row (rows avg E/N=16),
//    coalesced 8B loads + shfl_down(width=16) reduction

#define TPB 256
#define CG_ITERS 20
#define TOL2 1e-8f   // (CG_TOL=1e-4)^2

__device__ inline float fasi(float f) { return f; }

__device__ inline void block_reduce1_atomic(float v1, float* d1) {
#pragma unroll
  for (int o = 32; o; o >>= 1) v1 += __shfl_down(v1, o, 64);
  __shared__ float s1[TPB / 64];
  int lane = threadIdx.x & 63, wid = threadIdx.x >> 6;
  if (lane == 0) s1[wid] = v1;
  __syncthreads();
  if (threadIdx.x == 0) {
    float t1 = 0.f;
#pragma unroll
    for (int k = 0; k < TPB / 64; k++) t1 += s1[k];
    atomicAdd(d1, t1);
  }
}

__device__ inline void block_reduce2_atomic(float v1, float v2, float* d1, float* d2) {
#pragma unroll
  for (int o = 32; o; o >>= 1) {
    v1 += __shfl_down(v1, o, 64);
    v2 += __shfl_down(v2, o, 64);
  }
  __shared__ float s1[TPB / 64], s2[TPB / 64];
  int lane = threadIdx.x & 63, wid = threadIdx.x >> 6;
  if (lane == 0) { s1[wid] = v1; s2[wid] = v2; }
  __syncthreads();
  if (threadIdx.x == 0) {
    float t1 = 0.f, t2 = 0.f;
#pragma unroll
    for (int k = 0; k < TPB / 64; k++) { t1 += s1[k]; t2 += s2[k]; }
    atomicAdd(d1, t1);
    atomicAdd(d2, t2);
  }
}

// ---- histogram only: cnt[dst]++ ----
__global__ __launch_bounds__(TPB) void hist(
    const int* __restrict__ ei, unsigned* __restrict__ cnt, int E) {
  int e = blockIdx.x * TPB + threadIdx.x;
  if (e >= E) return;
  atomicAdd(&cnt[ei[E + e]], 1u);
}

// ---- scan (1024 elems / block) ----
__global__ __launch_bounds__(TPB) void scan_blocks(
    const unsigned* __restrict__ cnt, unsigned* __restrict__ offs,
    unsigned* __restrict__ btot, int n) {
  __shared__ unsigned sd[TPB];
  int t = threadIdx.x;
  int base = blockIdx.x * 1024 + t * 4;
  unsigned v0 = 0, v1 = 0, v2 = 0, v3 = 0;
  if (base + 0 < n) v0 = cnt[base + 0];
  if (base + 1 < n) v1 = cnt[base + 1];
  if (base + 2 < n) v2 = cnt[base + 2];
  if (base + 3 < n) v3 = cnt[base + 3];
  unsigned local = v0 + v1 + v2 + v3;
  sd[t] = local;
  __syncthreads();
  for (int o = 1; o < TPB; o <<= 1) {
    unsigned x = (t >= o) ? sd[t - o] : 0u;
    __syncthreads();
    sd[t] += x;
    __syncthreads();
  }
  unsigned excl = sd[t] - local;
  if (base + 0 < n) offs[base + 0] = excl; excl += v0;
  if (base + 1 < n) offs[base + 1] = excl; excl += v1;
  if (base + 2 < n) offs[base + 2] = excl; excl += v2;
  if (base + 3 < n) offs[base + 3] = excl;
  if (t == TPB - 1) btot[blockIdx.x] = sd[TPB - 1];
}

__global__ __launch_bounds__(512) void scan_totals(unsigned* __restrict__ btot, int nb) {
  __shared__ unsigned sd[512];
  int t = threadIdx.x;
  unsigned v = (t < nb) ? btot[t] : 0u;
  sd[t] = v;
  __syncthreads();
  for (int o = 1; o < 512; o <<= 1) {
    unsigned x = (t >= o) ? sd[t - o] : 0u;
    __syncthreads();
    sd[t] += x;
    __syncthreads();
  }
  if (t < nb) btot[t] = sd[t] - v;  // exclusive
}

__global__ __launch_bounds__(TPB) void scan_add(
    unsigned* __restrict__ offs, unsigned* __restrict__ wp,
    const unsigned* __restrict__ btot, int n, unsigned total) {
  int i = blockIdx.x * TPB + threadIdx.x;
  if (i < n) {
    unsigned v = offs[i] + btot[i >> 10];
    offs[i] = v;
    wp[i] = v;
  }
  if (i == 0) offs[n] = total;
}

// ---- bucket edges by dst; carry (src,w) and (eid,flux) payloads ----
__global__ __launch_bounds__(TPB) void scatter_edges(
    const int* __restrict__ ei, const float* __restrict__ u_hat,
    const float* __restrict__ fn, const float* __restrict__ fa,
    const float* __restrict__ fd, unsigned* __restrict__ wp,
    int2* __restrict__ csr_sw, int2* __restrict__ csr_ef, int E) {
  int e = blockIdx.x * TPB + threadIdx.x;
  if (e >= E) return;
  int s = ei[e], d = ei[E + e];
  float area = fa[e];
  float w = area / fmaxf(fd[e], 1e-8f);
  float ux = 0.5f * (u_hat[3 * s]     + u_hat[3 * d]);
  float uy = 0.5f * (u_hat[3 * s + 1] + u_hat[3 * d + 1]);
  float uz = 0.5f * (u_hat[3 * s + 2] + u_hat[3 * d + 2]);
  float flux = (ux * fn[3 * e] + uy * fn[3 * e + 1] + uz * fn[3 * e + 2]) * area;
  unsigned pos = atomicAdd(&wp[d], 1u);
  csr_sw[pos] = make_int2(s, __float_as_int(w));
  csr_ef[pos] = make_int2(e, __float_as_int(flux));
}

// ---- CG setup via CSR row sums: diag = sum w, div = sum flux ----
// 16 lanes per row.
__global__ __launch_bounds__(TPB) void node_setup(
    const int2* __restrict__ csr_sw, const int2* __restrict__ csr_ef,
    const unsigned* __restrict__ offs, const float* __restrict__ cv,
    float* __restrict__ diag, float* __restrict__ r, float* __restrict__ p,
    float* __restrict__ phi, float* __restrict__ minv,
    float* __restrict__ rz0, float* __restrict__ rr0, int N) {
  int g = blockIdx.x * (TPB / 16) + (threadIdx.x >> 4);
  int l = threadIdx.x & 15;
  float rzv = 0.f, rrv = 0.f;
  if (g < N) {
    unsigned a = offs[g], bnd = offs[g + 1];
    float wsum = 0.f, fsum = 0.f;
    for (unsigned j = a + l; j < bnd; j += 16) {
      wsum += __int_as_float(csr_sw[j].y);
      fsum += __int_as_float(csr_ef[j].y);
    }
#pragma unroll
    for (int o = 8; o; o >>= 1) {
      wsum += __shfl_down(wsum, o, 16);
      fsum += __shfl_down(fsum, o, 16);
    }
    if (l == 0) {
      float vol = fmaxf(cv[g], 1e-12f);
      float b = fsum / vol;
      float mi = 1.0f / fmaxf(wsum, 1e-8f);
      diag[g] = wsum;
      minv[g] = mi;
      r[g] = b;
      phi[g] = 0.f;
      float pi = mi * b;
      p[g] = pi;
      rzv = b * pi;
      rrv = b * b;
    }
  }
  block_reduce2_atomic(rzv, rrv, rz0, rr0);
}

// ---- ap = diag*p - sum_j w_j * p[src_j]; pAp += p.ap  (16 lanes/row) ----
__global__ __launch_bounds__(TPB) void matvec(
    const float* __restrict__ p, const float* __restrict__ diag,
    const unsigned* __restrict__ offs, const int2* __restrict__ csr_sw,
    float* __restrict__ ap, float* __restrict__ pap_slot, int N) {
  int g = blockIdx.x * (TPB / 16) + (threadIdx.x >> 4);
  int l = threadIdx.x & 15;
  float contrib = 0.f;
  if (g < N) {
    unsigned a = offs[g], bnd = offs[g + 1];
    float sum = 0.f;
    for (unsigned j = a + l; j < bnd; j += 16) {
      int2 sw = csr_sw[j];
      sum += __int_as_float(sw.y) * p[sw.x];
    }
#pragma unroll
    for (int o = 8; o; o >>= 1) sum += __shfl_down(sum, o, 16);
    if (l == 0) {
      float pi = p[g];
      float api = diag[g] * pi - sum;
      ap[g] = api;
      contrib = pi * api;
    }
  }
  block_reduce1_atomic(contrib, pap_slot);
}

// ---- gated phi/r update + rz/rr dots for next iter ----
__global__ __launch_bounds__(TPB) void cg_update(
    float* __restrict__ phi, float* __restrict__ r, const float* __restrict__ p,
    const float* __restrict__ ap, const float* __restrict__ minv,
    const float* __restrict__ rz_it, const float* __restrict__ pap_it,
    const float* __restrict__ rr_it, float* __restrict__ rz_next,
    float* __restrict__ rr_next, int N) {
  int i = blockIdx.x * TPB + threadIdx.x;
  float rzv = 0.f, rrv = 0.f;
  if (i < N) {
    bool act = (*rr_it >= TOL2);
    float alpha = (*rz_it) / ((*pap_it) + 1e-12f);
    float ri = r[i];
    if (act) {
      phi[i] += alpha * p[i];
      ri -= alpha * ap[i];
      r[i] = ri;
    }
    float zi = minv[i] * ri;
    rzv = ri * zi;
    rrv = ri * ri;
  }
  block_reduce2_atomic(rzv, rrv, rz_next, rr_next);
}

// ---- gated p = z + beta*p ----
__global__ __launch_bounds__(TPB) void p_update(
    float* __restrict__ p, const float* __restrict__ r,
    const float* __restrict__ minv, const float* __restrict__ rz_next,
    const float* __restrict__ rz_it, const float* __restrict__ rr_it, int N) {
  int i = blockIdx.x * TPB + threadIdx.x;
  if (i >= N) return;
  if (*rr_it >= TOL2) {
    float beta = (*rz_next) / ((*rz_it) + 1e-12f);
    p[i] = minv[i] * r[i] + beta * p[i];
  }
}

// ---- pressure correction + output (16 lanes/row) ----
__global__ __launch_bounds__(TPB) void finalize(
    const float* __restrict__ u_hat, const float* __restrict__ cv,
    const float* __restrict__ phi, const unsigned* __restrict__ offs,
    const int2* __restrict__ csr_sw, const int2* __restrict__ csr_ef,
    const float* __restrict__ fn, float* __restrict__ out, int N) {
  int g = blockIdx.x * (TPB / 16) + (threadIdx.x >> 4);
  int l = threadIdx.x & 15;
  if (g >= N) return;
  unsigned a = offs[g], bnd = offs[g + 1];
  float gx = 0.f, gy = 0.f, gz = 0.f;
  for (unsigned j = a + l; j < bnd; j += 16) {
    int2 sw = csr_sw[j];
    float t = __int_as_float(sw.y) * phi[sw.x];
    int e = csr_ef[j].x;
    gx += t * fn[3 * e];
    gy += t * fn[3 * e + 1];
    gz += t * fn[3 * e + 2];
  }
#pragma unroll
  for (int o = 8; o; o >>= 1) {
    gx += __shfl_down(gx, o, 16);
    gy += __shfl_down(gy, o, 16);
    gz += __shfl_down(gz, o, 16);
  }
  if (l == 0) {
    float iv = 1.0f / fmaxf(cv[g], 1e-12f);
    out[3 * g]     = u_hat[3 * g]     - gx * iv;
    out[3 * g + 1] = u_hat[3 * g + 1] - gy * iv;
    out[3 * g + 2] = u_hat[3 * g + 2] - gz * iv;
    out[3 * N + g] = phi[g];
  }
}

extern "C" void kernel_launch(void* const* d_in, const int* in_sizes, int n_in,
                              void* d_out, int out_size, void* d_ws, size_t ws_size,
                              hipStream_t stream) {
  const float* u_hat = (const float*)d_in[0];
  const int*   ei    = (const int*)d_in[1];
  const float* fn    = (const float*)d_in[2];
  const float* fa    = (const float*)d_in[3];
  const float* fd    = (const float*)d_in[4];
  const float* cv    = (const float*)d_in[5];
  float* out = (float*)d_out;

  const int N = in_sizes[0] / 3;   // 500,000
  const int E = in_sizes[1] / 2;   // 8,000,000

  // ---- workspace bump allocator (256B aligned) ----
  char* base = (char*)d_ws;
  size_t off = 0;
  auto alloc = [&](size_t bytes) -> void* {
    void* ptr = base + off;
    off = (off + bytes + 255) & ~size_t(255);
    return ptr;
  };
  // zero region first (one memset covers it)
  unsigned* cnt  = (unsigned*)alloc((size_t)N * 4);
  float*    scal = (float*)alloc(512);  // rz[21] | rr[21] | pAp[20]
  size_t zero_bytes = off;
  float* rz  = scal;       // 21 slots
  float* rr  = scal + 32;  // 21 slots
  float* pap = scal + 64;  // 20 slots
  // non-zeroed scratch
  unsigned* offs    = (unsigned*)alloc((size_t)(N + 1) * 4);
  unsigned* wp      = (unsigned*)alloc((size_t)N * 4);
  unsigned* btot    = (unsigned*)alloc(512 * 4);
  float*    diag    = (float*)alloc((size_t)N * 4);
  float*    minv    = (float*)alloc((size_t)N * 4);
  float*    phi     = (float*)alloc((size_t)N * 4);
  float*    rvec    = (float*)alloc((size_t)N * 4);
  float*    pvec    = (float*)alloc((size_t)N * 4);
  float*    ap      = (float*)alloc((size_t)N * 4);
  int2*     csr_sw  = (int2*)alloc((size_t)E * 8);
  int2*     csr_ef  = (int2*)alloc((size_t)E * 8);
  (void)ws_size; (void)n_in; (void)out_size;

  const int gridE = (E + TPB - 1) / TPB;
  const int gridN = (N + TPB - 1) / TPB;
  const int rowsPerBlk = TPB / 16;
  const int gridR = (N + rowsPerBlk - 1) / rowsPerBlk;
  const int nbScan = (N + 1023) / 1024;  // <= 512

  hipMemsetAsync(base, 0, zero_bytes, stream);

  hist<<<gridE, TPB, 0, stream>>>(ei, cnt, E);

  scan_blocks<<<nbScan, TPB, 0, stream>>>(cnt, offs, btot, N);
  scan_totals<<<1, 512, 0, stream>>>(btot, nbScan);
  scan_add<<<gridN, TPB, 0, stream>>>(offs, wp, btot, N, (unsigned)E);

  scatter_edges<<<gridE, TPB, 0, stream>>>(ei, u_hat, fn, fa, fd, wp,
                                           csr_sw, csr_ef, E);

  node_setup<<<gridR, TPB, 0, stream>>>(csr_sw, csr_ef, offs, cv, diag,
                                        rvec, pvec, phi, minv,
                                        &rz[0], &rr[0], N);

  for (int it = 0; it < CG_ITERS; it++) {
    matvec<<<gridR, TPB, 0, stream>>>(pvec, diag, offs, csr_sw, ap,
                                      &pap[it], N);
    cg_update<<<gridN, TPB, 0, stream>>>(phi, rvec, pvec, ap, minv,
                                         &rz[it], &pap[it], &rr[it],
                                         &rz[it + 1], &rr[it + 1], N);
    if (it < CG_ITERS - 1) {
      p_update<<<gridN, TPB, 0, stream>>>(pvec, rvec, minv,
                                          &rz[it + 1], &rz[it], &rr[it], N);
    }
  }

  finalize<<<gridR, TPB, 0, stream>>>(u_hat, cv, phi, offs, csr_sw, csr_ef,
                                      fn, out, N);
}

// Round 3
// 2843.820 us; speedup vs baseline: 3.7173x; 3.7173x over previous
//
#include <hip/hip_runtime.h>

// PressureProjection on MI355X — round 3.
// Key change vs R2: NO same-address atomic reductions anywhere. Reductions
// write per-block partials (plain stores); consumer kernels re-reduce the
// 2048-entry partial arrays at block start. Per-iteration partial slots keep
// the graph static. scatter's latency chain split: flux computed in its own
// coalesced kernel; scatter only does the counting-sort placement.

#define TPB 256
#define KB 2048          // grid size for node/CG kernels (256 CU x 8 blocks)
#define CG_ITERS 20
#define TOL2 1e-8f       // (CG_TOL=1e-4)^2

struct Sum3 { float a, b, c; };

// block-wide sums of three arrays of length n, broadcast to all threads
__device__ inline Sum3 block_sum3_bcast(const float* __restrict__ A,
                                        const float* __restrict__ B,
                                        const float* __restrict__ C, int n) {
  float va = 0.f, vb = 0.f, vc = 0.f;
  for (int k = threadIdx.x; k < n; k += TPB) { va += A[k]; vb += B[k]; vc += C[k]; }
#pragma unroll
  for (int o = 32; o; o >>= 1) {
    va += __shfl_down(va, o, 64);
    vb += __shfl_down(vb, o, 64);
    vc += __shfl_down(vc, o, 64);
  }
  __shared__ float sa[TPB / 64], sb[TPB / 64], sc[TPB / 64], bc[3];
  int lane = threadIdx.x & 63, wid = threadIdx.x >> 6;
  if (lane == 0) { sa[wid] = va; sb[wid] = vb; sc[wid] = vc; }
  __syncthreads();
  if (threadIdx.x == 0) {
    float ta = 0.f, tb = 0.f, tc = 0.f;
#pragma unroll
    for (int k = 0; k < TPB / 64; k++) { ta += sa[k]; tb += sb[k]; tc += sc[k]; }
    bc[0] = ta; bc[1] = tb; bc[2] = tc;
  }
  __syncthreads();
  Sum3 r{bc[0], bc[1], bc[2]};
  __syncthreads();
  return r;
}

// block reduce -> thread0 plain-stores to d1 (one partial per block)
__device__ inline void block_reduce1_store(float v1, float* d1) {
#pragma unroll
  for (int o = 32; o; o >>= 1) v1 += __shfl_down(v1, o, 64);
  __shared__ float s1[TPB / 64];
  int lane = threadIdx.x & 63, wid = threadIdx.x >> 6;
  if (lane == 0) s1[wid] = v1;
  __syncthreads();
  if (threadIdx.x == 0) {
    float t1 = 0.f;
#pragma unroll
    for (int k = 0; k < TPB / 64; k++) t1 += s1[k];
    *d1 = t1;
  }
}

__device__ inline void block_reduce2_store(float v1, float v2, float* d1, float* d2) {
#pragma unroll
  for (int o = 32; o; o >>= 1) {
    v1 += __shfl_down(v1, o, 64);
    v2 += __shfl_down(v2, o, 64);
  }
  __shared__ float s1[TPB / 64], s2[TPB / 64];
  int lane = threadIdx.x & 63, wid = threadIdx.x >> 6;
  if (lane == 0) { s1[wid] = v1; s2[wid] = v2; }
  __syncthreads();
  if (threadIdx.x == 0) {
    float t1 = 0.f, t2 = 0.f;
#pragma unroll
    for (int k = 0; k < TPB / 64; k++) { t1 += s1[k]; t2 += s2[k]; }
    *d1 = t1;
    *d2 = t2;
  }
}

// ---- histogram: cnt[dst]++ (8M spread-address atomics, once) ----
__global__ __launch_bounds__(TPB) void hist(
    const int* __restrict__ ei, unsigned* __restrict__ cnt, int E) {
  int e = blockIdx.x * TPB + threadIdx.x;
  if (e >= E) return;
  atomicAdd(&cnt[ei[E + e]], 1u);
}

// ---- flux[e], coalesced streams + u_hat gathers (latency isolated here) ----
__global__ __launch_bounds__(TPB) void flux_kernel(
    const int* __restrict__ ei, const float* __restrict__ u_hat,
    const float* __restrict__ fn, const float* __restrict__ fa,
    float* __restrict__ flux, int E) {
  int e = blockIdx.x * TPB + threadIdx.x;
  if (e >= E) return;
  int s = ei[e], d = ei[E + e];
  float ux = 0.5f * (u_hat[3 * s]     + u_hat[3 * d]);
  float uy = 0.5f * (u_hat[3 * s + 1] + u_hat[3 * d + 1]);
  float uz = 0.5f * (u_hat[3 * s + 2] + u_hat[3 * d + 2]);
  flux[e] = (ux * fn[3 * e] + uy * fn[3 * e + 1] + uz * fn[3 * e + 2]) * fa[e];
}

// ---- scan (1024 elems / block) ----
__global__ __launch_bounds__(TPB) void scan_blocks(
    const unsigned* __restrict__ cnt, unsigned* __restrict__ offs,
    unsigned* __restrict__ btot, int n) {
  __shared__ unsigned sd[TPB];
  int t = threadIdx.x;
  int base = blockIdx.x * 1024 + t * 4;
  unsigned v0 = 0, v1 = 0, v2 = 0, v3 = 0;
  if (base + 0 < n) v0 = cnt[base + 0];
  if (base + 1 < n) v1 = cnt[base + 1];
  if (base + 2 < n) v2 = cnt[base + 2];
  if (base + 3 < n) v3 = cnt[base + 3];
  unsigned local = v0 + v1 + v2 + v3;
  sd[t] = local;
  __syncthreads();
  for (int o = 1; o < TPB; o <<= 1) {
    unsigned x = (t >= o) ? sd[t - o] : 0u;
    __syncthreads();
    sd[t] += x;
    __syncthreads();
  }
  unsigned excl = sd[t] - local;
  if (base + 0 < n) offs[base + 0] = excl; excl += v0;
  if (base + 1 < n) offs[base + 1] = excl; excl += v1;
  if (base + 2 < n) offs[base + 2] = excl; excl += v2;
  if (base + 3 < n) offs[base + 3] = excl;
  if (t == TPB - 1) btot[blockIdx.x] = sd[TPB - 1];
}

__global__ __launch_bounds__(512) void scan_totals(unsigned* __restrict__ btot, int nb) {
  __shared__ unsigned sd[512];
  int t = threadIdx.x;
  unsigned v = (t < nb) ? btot[t] : 0u;
  sd[t] = v;
  __syncthreads();
  for (int o = 1; o < 512; o <<= 1) {
    unsigned x = (t >= o) ? sd[t - o] : 0u;
    __syncthreads();
    sd[t] += x;
    __syncthreads();
  }
  if (t < nb) btot[t] = sd[t] - v;  // exclusive
}

__global__ __launch_bounds__(TPB) void scan_add(
    unsigned* __restrict__ offs, unsigned* __restrict__ wp,
    const unsigned* __restrict__ btot, int n, unsigned total) {
  int i = blockIdx.x * TPB + threadIdx.x;
  if (i < n) {
    unsigned v = offs[i] + btot[i >> 10];
    offs[i] = v;
    wp[i] = v;
  }
  if (i == 0) offs[n] = total;
}

// ---- counting-sort placement only: (src,w) 8B + eid 4B + flux 4B ----
__global__ __launch_bounds__(TPB) void scatter_edges(
    const int* __restrict__ ei, const float* __restrict__ fa,
    const float* __restrict__ fd, const float* __restrict__ flux,
    unsigned* __restrict__ wp, int2* __restrict__ csr_sw,
    int* __restrict__ csr_eid, float* __restrict__ csr_flux, int E) {
  int e = blockIdx.x * TPB + threadIdx.x;
  if (e >= E) return;
  int s = ei[e], d = ei[E + e];
  float w = fa[e] / fmaxf(fd[e], 1e-8f);
  float fl = flux[e];
  unsigned pos = atomicAdd(&wp[d], 1u);
  csr_sw[pos] = make_int2(s, __float_as_int(w));
  csr_eid[pos] = e;
  csr_flux[pos] = fl;
}

// ---- CG setup via CSR row sums (8 lanes/row, grid-stride) ----
__global__ __launch_bounds__(TPB) void node_setup(
    const int2* __restrict__ csr_sw, const float* __restrict__ csr_flux,
    const unsigned* __restrict__ offs, const float* __restrict__ cv,
    float* __restrict__ diag, float* __restrict__ r, float* __restrict__ p,
    float* __restrict__ phi, float* __restrict__ minv,
    float* __restrict__ rz_part, float* __restrict__ rr_part, int N) {
  const int gpb = TPB / 8;                       // 32 groups per block
  const int stride = KB * gpb;
  int g0 = blockIdx.x * gpb + (threadIdx.x >> 3);
  int l = threadIdx.x & 7;
  float rzacc = 0.f, rracc = 0.f;
  for (int g = g0; g < N; g += stride) {
    unsigned a = offs[g], bnd = offs[g + 1];
    float wsum = 0.f, fsum = 0.f;
    for (unsigned j = a + l; j < bnd; j += 8) {
      wsum += __int_as_float(csr_sw[j].y);
      fsum += csr_flux[j];
    }
#pragma unroll
    for (int o = 4; o; o >>= 1) {
      wsum += __shfl_down(wsum, o, 8);
      fsum += __shfl_down(fsum, o, 8);
    }
    if (l == 0) {
      float vol = fmaxf(cv[g], 1e-12f);
      float b = fsum / vol;
      float mi = 1.0f / fmaxf(wsum, 1e-8f);
      diag[g] = wsum;
      minv[g] = mi;
      r[g] = b;
      phi[g] = 0.f;
      float pi = mi * b;
      p[g] = pi;
      rzacc += b * pi;
      rracc += b * b;
    }
  }
  block_reduce2_store(rzacc, rracc, &rz_part[blockIdx.x], &rr_part[blockIdx.x]);
}

// ---- ap = diag*p - sum w*p[src]; per-block pAp partial (8 lanes/row) ----
__global__ __launch_bounds__(TPB) void matvec(
    const float* __restrict__ p, const float* __restrict__ diag,
    const unsigned* __restrict__ offs, const int2* __restrict__ csr_sw,
    float* __restrict__ ap, float* __restrict__ pap_part, int N) {
  const int gpb = TPB / 8;
  const int stride = KB * gpb;
  int g0 = blockIdx.x * gpb + (threadIdx.x >> 3);
  int l = threadIdx.x & 7;
  float acc = 0.f;
  for (int g = g0; g < N; g += stride) {
    unsigned a = offs[g], bnd = offs[g + 1];
    float sum = 0.f;
    for (unsigned j = a + l; j < bnd; j += 8) {
      int2 sw = csr_sw[j];
      sum += __int_as_float(sw.y) * p[sw.x];
    }
#pragma unroll
    for (int o = 4; o; o >>= 1) sum += __shfl_down(sum, o, 8);
    if (l == 0) {
      float pi = p[g];
      float api = diag[g] * pi - sum;
      ap[g] = api;
      acc += pi * api;
    }
  }
  block_reduce1_store(acc, &pap_part[blockIdx.x]);
}

// ---- gated phi/r update; emits rz/rr partials for next iter ----
__global__ __launch_bounds__(TPB) void cg_update(
    float* __restrict__ phi, float* __restrict__ r, const float* __restrict__ p,
    const float* __restrict__ ap, const float* __restrict__ minv,
    const float* __restrict__ pap_it, const float* __restrict__ rz_it,
    const float* __restrict__ rr_it, float* __restrict__ rz_next,
    float* __restrict__ rr_next, int N) {
  Sum3 s = block_sum3_bcast(pap_it, rz_it, rr_it, KB);
  bool act = (s.c >= TOL2);
  float alpha = s.b / (s.a + 1e-12f);
  float rzacc = 0.f, rracc = 0.f;
  for (int i = blockIdx.x * TPB + threadIdx.x; i < N; i += KB * TPB) {
    float ri = r[i];
    if (act) {
      phi[i] += alpha * p[i];
      ri -= alpha * ap[i];
      r[i] = ri;
    }
    float zi = minv[i] * ri;
    rzacc += ri * zi;
    rracc += ri * ri;
  }
  block_reduce2_store(rzacc, rracc, &rz_next[blockIdx.x], &rr_next[blockIdx.x]);
}

// ---- gated p = z + beta*p ----
__global__ __launch_bounds__(TPB) void p_update(
    float* __restrict__ p, const float* __restrict__ r,
    const float* __restrict__ minv, const float* __restrict__ rz_next,
    const float* __restrict__ rz_it, const float* __restrict__ rr_it, int N) {
  Sum3 s = block_sum3_bcast(rz_next, rz_it, rr_it, KB);
  if (s.c < TOL2) return;  // frozen: p unchanged
  float beta = s.a / (s.b + 1e-12f);
  for (int i = blockIdx.x * TPB + threadIdx.x; i < N; i += KB * TPB) {
    p[i] = minv[i] * r[i] + beta * p[i];
  }
}

// ---- pressure correction + output (8 lanes/row, grid-stride) ----
__global__ __launch_bounds__(TPB) void finalize(
    const float* __restrict__ u_hat, const float* __restrict__ cv,
    const float* __restrict__ phi, const unsigned* __restrict__ offs,
    const int2* __restrict__ csr_sw, const int* __restrict__ csr_eid,
    const float* __restrict__ fn, float* __restrict__ out, int N) {
  const int gpb = TPB / 8;
  const int stride = KB * gpb;
  int g0 = blockIdx.x * gpb + (threadIdx.x >> 3);
  int l = threadIdx.x & 7;
  for (int g = g0; g < N; g += stride) {
    unsigned a = offs[g], bnd = offs[g + 1];
    float gx = 0.f, gy = 0.f, gz = 0.f;
    for (unsigned j = a + l; j < bnd; j += 8) {
      int2 sw = csr_sw[j];
      float t = __int_as_float(sw.y) * phi[sw.x];
      int e = csr_eid[j];
      gx += t * fn[3 * e];
      gy += t * fn[3 * e + 1];
      gz += t * fn[3 * e + 2];
    }
#pragma unroll
    for (int o = 4; o; o >>= 1) {
      gx += __shfl_down(gx, o, 8);
      gy += __shfl_down(gy, o, 8);
      gz += __shfl_down(gz, o, 8);
    }
    if (l == 0) {
      float iv = 1.0f / fmaxf(cv[g], 1e-12f);
      out[3 * g]     = u_hat[3 * g]     - gx * iv;
      out[3 * g + 1] = u_hat[3 * g + 1] - gy * iv;
      out[3 * g + 2] = u_hat[3 * g + 2] - gz * iv;
      out[3 * N + g] = phi[g];
    }
  }
}

extern "C" void kernel_launch(void* const* d_in, const int* in_sizes, int n_in,
                              void* d_out, int out_size, void* d_ws, size_t ws_size,
                              hipStream_t stream) {
  const float* u_hat = (const float*)d_in[0];
  const int*   ei    = (const int*)d_in[1];
  const float* fn    = (const float*)d_in[2];
  const float* fa    = (const float*)d_in[3];
  const float* fd    = (const float*)d_in[4];
  const float* cv    = (const float*)d_in[5];
  float* out = (float*)d_out;

  const int N = in_sizes[0] / 3;   // 500,000
  const int E = in_sizes[1] / 2;   // 8,000,000

  // ---- workspace bump allocator (256B aligned); total ~147 MB ----
  char* base = (char*)d_ws;
  size_t off = 0;
  auto alloc = [&](size_t bytes) -> void* {
    void* ptr = base + off;
    off = (off + bytes + 255) & ~size_t(255);
    return ptr;
  };
  // zero region first (single memset)
  unsigned* cnt = (unsigned*)alloc((size_t)N * 4);
  size_t zero_bytes = off;
  // non-zeroed scratch
  unsigned* offs     = (unsigned*)alloc((size_t)(N + 1) * 4);
  unsigned* wp       = (unsigned*)alloc((size_t)N * 4);
  unsigned* btot     = (unsigned*)alloc(512 * 4);
  float*    diag     = (float*)alloc((size_t)N * 4);
  float*    minv     = (float*)alloc((size_t)N * 4);
  float*    phi      = (float*)alloc((size_t)N * 4);
  float*    rvec     = (float*)alloc((size_t)N * 4);
  float*    pvec     = (float*)alloc((size_t)N * 4);
  float*    ap       = (float*)alloc((size_t)N * 4);
  float*    flux     = (float*)alloc((size_t)E * 4);
  // partials: rz/rr per iter 0..20, pap per iter 0..19
  float*    rzrr     = (float*)alloc((size_t)(2 * (CG_ITERS + 1)) * KB * 4);
  float*    papp     = (float*)alloc((size_t)CG_ITERS * KB * 4);
  int2*     csr_sw   = (int2*)alloc((size_t)E * 8);
  int*      csr_eid  = (int*)alloc((size_t)E * 4);
  float*    csr_flux = (float*)alloc((size_t)E * 4);
  (void)ws_size; (void)n_in; (void)out_size;

  auto rz_part = [&](int it) { return rzrr + (size_t)(2 * it) * KB; };
  auto rr_part = [&](int it) { return rzrr + (size_t)(2 * it + 1) * KB; };
  auto pap_part = [&](int it) { return papp + (size_t)it * KB; };

  const int gridE = (E + TPB - 1) / TPB;
  const int gridN = (N + TPB - 1) / TPB;
  const int nbScan = (N + 1023) / 1024;  // <= 512

  hipMemsetAsync(base, 0, zero_bytes, stream);

  hist<<<gridE, TPB, 0, stream>>>(ei, cnt, E);
  flux_kernel<<<gridE, TPB, 0, stream>>>(ei, u_hat, fn, fa, flux, E);

  scan_blocks<<<nbScan, TPB, 0, stream>>>(cnt, offs, btot, N);
  scan_totals<<<1, 512, 0, stream>>>(btot, nbScan);
  scan_add<<<gridN, TPB, 0, stream>>>(offs, wp, btot, N, (unsigned)E);

  scatter_edges<<<gridE, TPB, 0, stream>>>(ei, fa, fd, flux, wp,
                                           csr_sw, csr_eid, csr_flux, E);

  node_setup<<<KB, TPB, 0, stream>>>(csr_sw, csr_flux, offs, cv, diag,
                                     rvec, pvec, phi, minv,
                                     rz_part(0), rr_part(0), N);

  for (int it = 0; it < CG_ITERS; it++) {
    matvec<<<KB, TPB, 0, stream>>>(pvec, diag, offs, csr_sw, ap,
                                   pap_part(it), N);
    cg_update<<<KB, TPB, 0, stream>>>(phi, rvec, pvec, ap, minv,
                                      pap_part(it), rz_part(it), rr_part(it),
                                      rz_part(it + 1), rr_part(it + 1), N);
    if (it < CG_ITERS - 1) {
      p_update<<<KB, TPB, 0, stream>>>(pvec, rvec, minv,
                                       rz_part(it + 1), rz_part(it),
                                       rr_part(it), N);
    }
  }

  finalize<<<KB, TPB, 0, stream>>>(u_hat, cv, phi, offs, csr_sw, csr_eid,
                                   fn, out, N);
}

// Round 4
// 2630.451 us; speedup vs baseline: 4.0188x; 1.0811x over previous
//
#include <hip/hip_runtime.h>

// PressureProjection on MI355X — round 4.
// Changes vs R3 (scatter latency-bound on atomic->store chain):
//  * rank trick: hist stores atomicAdd's return as rank[e]; scatter computes
//    pos = offs[dst] + rank[e] -> NO atomic in scatter, stores fire-and-forget
//  * flux fused into scatter (separate flux pass removed)
//  * payloads merged to two 8B stores: (src,w) + (eid,flux)

#define TPB 256
#define KB 2048          // grid size for node/CG kernels (256 CU x 8 blocks)
#define CG_ITERS 20
#define TOL2 1e-8f       // (CG_TOL=1e-4)^2

struct Sum3 { float a, b, c; };

// block-wide sums of three arrays of length n, broadcast to all threads
__device__ inline Sum3 block_sum3_bcast(const float* __restrict__ A,
                                        const float* __restrict__ B,
                                        const float* __restrict__ C, int n) {
  float va = 0.f, vb = 0.f, vc = 0.f;
  for (int k = threadIdx.x; k < n; k += TPB) { va += A[k]; vb += B[k]; vc += C[k]; }
#pragma unroll
  for (int o = 32; o; o >>= 1) {
    va += __shfl_down(va, o, 64);
    vb += __shfl_down(vb, o, 64);
    vc += __shfl_down(vc, o, 64);
  }
  __shared__ float sa[TPB / 64], sb[TPB / 64], sc[TPB / 64], bc[3];
  int lane = threadIdx.x & 63, wid = threadIdx.x >> 6;
  if (lane == 0) { sa[wid] = va; sb[wid] = vb; sc[wid] = vc; }
  __syncthreads();
  if (threadIdx.x == 0) {
    float ta = 0.f, tb = 0.f, tc = 0.f;
#pragma unroll
    for (int k = 0; k < TPB / 64; k++) { ta += sa[k]; tb += sb[k]; tc += sc[k]; }
    bc[0] = ta; bc[1] = tb; bc[2] = tc;
  }
  __syncthreads();
  Sum3 r{bc[0], bc[1], bc[2]};
  __syncthreads();
  return r;
}

// block reduce -> thread0 plain-stores to d1 (one partial per block)
__device__ inline void block_reduce1_store(float v1, float* d1) {
#pragma unroll
  for (int o = 32; o; o >>= 1) v1 += __shfl_down(v1, o, 64);
  __shared__ float s1[TPB / 64];
  int lane = threadIdx.x & 63, wid = threadIdx.x >> 6;
  if (lane == 0) s1[wid] = v1;
  __syncthreads();
  if (threadIdx.x == 0) {
    float t1 = 0.f;
#pragma unroll
    for (int k = 0; k < TPB / 64; k++) t1 += s1[k];
    *d1 = t1;
  }
}

__device__ inline void block_reduce2_store(float v1, float v2, float* d1, float* d2) {
#pragma unroll
  for (int o = 32; o; o >>= 1) {
    v1 += __shfl_down(v1, o, 64);
    v2 += __shfl_down(v2, o, 64);
  }
  __shared__ float s1[TPB / 64], s2[TPB / 64];
  int lane = threadIdx.x & 63, wid = threadIdx.x >> 6;
  if (lane == 0) { s1[wid] = v1; s2[wid] = v2; }
  __syncthreads();
  if (threadIdx.x == 0) {
    float t1 = 0.f, t2 = 0.f;
#pragma unroll
    for (int k = 0; k < TPB / 64; k++) { t1 += s1[k]; t2 += s2[k]; }
    *d1 = t1;
    *d2 = t2;
  }
}

// ---- histogram + rank: rank[e] = cnt[dst]++ ----
__global__ __launch_bounds__(TPB) void hist(
    const int* __restrict__ ei, unsigned* __restrict__ cnt,
    unsigned* __restrict__ rank, int E) {
  int e = blockIdx.x * TPB + threadIdx.x;
  if (e >= E) return;
  rank[e] = atomicAdd(&cnt[ei[E + e]], 1u);
}

// ---- scan (1024 elems / block) ----
__global__ __launch_bounds__(TPB) void scan_blocks(
    const unsigned* __restrict__ cnt, unsigned* __restrict__ offs,
    unsigned* __restrict__ btot, int n) {
  __shared__ unsigned sd[TPB];
  int t = threadIdx.x;
  int base = blockIdx.x * 1024 + t * 4;
  unsigned v0 = 0, v1 = 0, v2 = 0, v3 = 0;
  if (base + 0 < n) v0 = cnt[base + 0];
  if (base + 1 < n) v1 = cnt[base + 1];
  if (base + 2 < n) v2 = cnt[base + 2];
  if (base + 3 < n) v3 = cnt[base + 3];
  unsigned local = v0 + v1 + v2 + v3;
  sd[t] = local;
  __syncthreads();
  for (int o = 1; o < TPB; o <<= 1) {
    unsigned x = (t >= o) ? sd[t - o] : 0u;
    __syncthreads();
    sd[t] += x;
    __syncthreads();
  }
  unsigned excl = sd[t] - local;
  if (base + 0 < n) offs[base + 0] = excl; excl += v0;
  if (base + 1 < n) offs[base + 1] = excl; excl += v1;
  if (base + 2 < n) offs[base + 2] = excl; excl += v2;
  if (base + 3 < n) offs[base + 3] = excl;
  if (t == TPB - 1) btot[blockIdx.x] = sd[TPB - 1];
}

__global__ __launch_bounds__(512) void scan_totals(unsigned* __restrict__ btot, int nb) {
  __shared__ unsigned sd[512];
  int t = threadIdx.x;
  unsigned v = (t < nb) ? btot[t] : 0u;
  sd[t] = v;
  __syncthreads();
  for (int o = 1; o < 512; o <<= 1) {
    unsigned x = (t >= o) ? sd[t - o] : 0u;
    __syncthreads();
    sd[t] += x;
    __syncthreads();
  }
  if (t < nb) btot[t] = sd[t] - v;  // exclusive
}

__global__ __launch_bounds__(TPB) void scan_add(
    unsigned* __restrict__ offs, const unsigned* __restrict__ btot,
    int n, unsigned total) {
  int i = blockIdx.x * TPB + threadIdx.x;
  if (i < n) offs[i] += btot[i >> 10];
  if (i == 0) offs[n] = total;
}

// ---- fused flux + counting-sort placement (no atomics) ----
__global__ __launch_bounds__(TPB) void scatter_edges(
    const int* __restrict__ ei, const float* __restrict__ u_hat,
    const float* __restrict__ fn, const float* __restrict__ fa,
    const float* __restrict__ fd, const unsigned* __restrict__ rank,
    const unsigned* __restrict__ offs, int2* __restrict__ csr_sw,
    int2* __restrict__ csr_ef, int E) {
  int e = blockIdx.x * TPB + threadIdx.x;
  if (e >= E) return;
  int s = ei[e], d = ei[E + e];
  float area = fa[e];
  float w = area / fmaxf(fd[e], 1e-8f);
  float ux = 0.5f * (u_hat[3 * s]     + u_hat[3 * d]);
  float uy = 0.5f * (u_hat[3 * s + 1] + u_hat[3 * d + 1]);
  float uz = 0.5f * (u_hat[3 * s + 2] + u_hat[3 * d + 2]);
  float flux = (ux * fn[3 * e] + uy * fn[3 * e + 1] + uz * fn[3 * e + 2]) * area;
  unsigned pos = offs[d] + rank[e];
  csr_sw[pos] = make_int2(s, __float_as_int(w));
  csr_ef[pos] = make_int2(e, __float_as_int(flux));
}

// ---- CG setup via CSR row sums (8 lanes/row, grid-stride) ----
__global__ __launch_bounds__(TPB) void node_setup(
    const int2* __restrict__ csr_sw, const int2* __restrict__ csr_ef,
    const unsigned* __restrict__ offs, const float* __restrict__ cv,
    float* __restrict__ diag, float* __restrict__ r, float* __restrict__ p,
    float* __restrict__ phi, float* __restrict__ minv,
    float* __restrict__ rz_part, float* __restrict__ rr_part, int N) {
  const int gpb = TPB / 8;                       // 32 groups per block
  const int stride = KB * gpb;
  int g0 = blockIdx.x * gpb + (threadIdx.x >> 3);
  int l = threadIdx.x & 7;
  float rzacc = 0.f, rracc = 0.f;
  for (int g = g0; g < N; g += stride) {
    unsigned a = offs[g], bnd = offs[g + 1];
    float wsum = 0.f, fsum = 0.f;
    for (unsigned j = a + l; j < bnd; j += 8) {
      wsum += __int_as_float(csr_sw[j].y);
      fsum += __int_as_float(csr_ef[j].y);
    }
#pragma unroll
    for (int o = 4; o; o >>= 1) {
      wsum += __shfl_down(wsum, o, 8);
      fsum += __shfl_down(fsum, o, 8);
    }
    if (l == 0) {
      float vol = fmaxf(cv[g], 1e-12f);
      float b = fsum / vol;
      float mi = 1.0f / fmaxf(wsum, 1e-8f);
      diag[g] = wsum;
      minv[g] = mi;
      r[g] = b;
      phi[g] = 0.f;
      float pi = mi * b;
      p[g] = pi;
      rzacc += b * pi;
      rracc += b * b;
    }
  }
  block_reduce2_store(rzacc, rracc, &rz_part[blockIdx.x], &rr_part[blockIdx.x]);
}

// ---- ap = diag*p - sum w*p[src]; per-block pAp partial (8 lanes/row) ----
__global__ __launch_bounds__(TPB) void matvec(
    const float* __restrict__ p, const float* __restrict__ diag,
    const unsigned* __restrict__ offs, const int2* __restrict__ csr_sw,
    float* __restrict__ ap, float* __restrict__ pap_part, int N) {
  const int gpb = TPB / 8;
  const int stride = KB * gpb;
  int g0 = blockIdx.x * gpb + (threadIdx.x >> 3);
  int l = threadIdx.x & 7;
  float acc = 0.f;
  for (int g = g0; g < N; g += stride) {
    unsigned a = offs[g], bnd = offs[g + 1];
    float sum = 0.f;
    for (unsigned j = a + l; j < bnd; j += 8) {
      int2 sw = csr_sw[j];
      sum += __int_as_float(sw.y) * p[sw.x];
    }
#pragma unroll
    for (int o = 4; o; o >>= 1) sum += __shfl_down(sum, o, 8);
    if (l == 0) {
      float pi = p[g];
      float api = diag[g] * pi - sum;
      ap[g] = api;
      acc += pi * api;
    }
  }
  block_reduce1_store(acc, &pap_part[blockIdx.x]);
}

// ---- gated phi/r update; emits rz/rr partials for next iter ----
__global__ __launch_bounds__(TPB) void cg_update(
    float* __restrict__ phi, float* __restrict__ r, const float* __restrict__ p,
    const float* __restrict__ ap, const float* __restrict__ minv,
    const float* __restrict__ pap_it, const float* __restrict__ rz_it,
    const float* __restrict__ rr_it, float* __restrict__ rz_next,
    float* __restrict__ rr_next, int N) {
  Sum3 s = block_sum3_bcast(pap_it, rz_it, rr_it, KB);
  bool act = (s.c >= TOL2);
  float alpha = s.b / (s.a + 1e-12f);
  float rzacc = 0.f, rracc = 0.f;
  for (int i = blockIdx.x * TPB + threadIdx.x; i < N; i += KB * TPB) {
    float ri = r[i];
    if (act) {
      phi[i] += alpha * p[i];
      ri -= alpha * ap[i];
      r[i] = ri;
    }
    float zi = minv[i] * ri;
    rzacc += ri * zi;
    rracc += ri * ri;
  }
  block_reduce2_store(rzacc, rracc, &rz_next[blockIdx.x], &rr_next[blockIdx.x]);
}

// ---- gated p = z + beta*p ----
__global__ __launch_bounds__(TPB) void p_update(
    float* __restrict__ p, const float* __restrict__ r,
    const float* __restrict__ minv, const float* __restrict__ rz_next,
    const float* __restrict__ rz_it, const float* __restrict__ rr_it, int N) {
  Sum3 s = block_sum3_bcast(rz_next, rz_it, rr_it, KB);
  if (s.c < TOL2) return;  // frozen: p unchanged
  float beta = s.a / (s.b + 1e-12f);
  for (int i = blockIdx.x * TPB + threadIdx.x; i < N; i += KB * TPB) {
    p[i] = minv[i] * r[i] + beta * p[i];
  }
}

// ---- pressure correction + output (8 lanes/row, grid-stride) ----
__global__ __launch_bounds__(TPB) void finalize(
    const float* __restrict__ u_hat, const float* __restrict__ cv,
    const float* __restrict__ phi, const unsigned* __restrict__ offs,
    const int2* __restrict__ csr_sw, const int2* __restrict__ csr_ef,
    const float* __restrict__ fn, float* __restrict__ out, int N) {
  const int gpb = TPB / 8;
  const int stride = KB * gpb;
  int g0 = blockIdx.x * gpb + (threadIdx.x >> 3);
  int l = threadIdx.x & 7;
  for (int g = g0; g < N; g += stride) {
    unsigned a = offs[g], bnd = offs[g + 1];
    float gx = 0.f, gy = 0.f, gz = 0.f;
    for (unsigned j = a + l; j < bnd; j += 8) {
      int2 sw = csr_sw[j];
      float t = __int_as_float(sw.y) * phi[sw.x];
      int e = csr_ef[j].x;
      gx += t * fn[3 * e];
      gy += t * fn[3 * e + 1];
      gz += t * fn[3 * e + 2];
    }
#pragma unroll
    for (int o = 4; o; o >>= 1) {
      gx += __shfl_down(gx, o, 8);
      gy += __shfl_down(gy, o, 8);
      gz += __shfl_down(gz, o, 8);
    }
    if (l == 0) {
      float iv = 1.0f / fmaxf(cv[g], 1e-12f);
      out[3 * g]     = u_hat[3 * g]     - gx * iv;
      out[3 * g + 1] = u_hat[3 * g + 1] - gy * iv;
      out[3 * g + 2] = u_hat[3 * g + 2] - gz * iv;
      out[3 * N + g] = phi[g];
    }
  }
}

extern "C" void kernel_launch(void* const* d_in, const int* in_sizes, int n_in,
                              void* d_out, int out_size, void* d_ws, size_t ws_size,
                              hipStream_t stream) {
  const float* u_hat = (const float*)d_in[0];
  const int*   ei    = (const int*)d_in[1];
  const float* fn    = (const float*)d_in[2];
  const float* fa    = (const float*)d_in[3];
  const float* fd    = (const float*)d_in[4];
  const float* cv    = (const float*)d_in[5];
  float* out = (float*)d_out;

  const int N = in_sizes[0] / 3;   // 500,000
  const int E = in_sizes[1] / 2;   // 8,000,000

  // ---- workspace bump allocator (256B aligned) ----
  char* base = (char*)d_ws;
  size_t off = 0;
  auto alloc = [&](size_t bytes) -> void* {
    void* ptr = base + off;
    off = (off + bytes + 255) & ~size_t(255);
    return ptr;
  };
  // zero region first (single memset)
  unsigned* cnt = (unsigned*)alloc((size_t)N * 4);
  size_t zero_bytes = off;
  // non-zeroed scratch
  unsigned* offs     = (unsigned*)alloc((size_t)(N + 1) * 4);
  unsigned* btot     = (unsigned*)alloc(512 * 4);
  unsigned* rank     = (unsigned*)alloc((size_t)E * 4);
  float*    diag     = (float*)alloc((size_t)N * 4);
  float*    minv     = (float*)alloc((size_t)N * 4);
  float*    phi      = (float*)alloc((size_t)N * 4);
  float*    rvec     = (float*)alloc((size_t)N * 4);
  float*    pvec     = (float*)alloc((size_t)N * 4);
  float*    ap       = (float*)alloc((size_t)N * 4);
  // partials: rz/rr per iter 0..20, pap per iter 0..19
  float*    rzrr     = (float*)alloc((size_t)(2 * (CG_ITERS + 1)) * KB * 4);
  float*    papp     = (float*)alloc((size_t)CG_ITERS * KB * 4);
  int2*     csr_sw   = (int2*)alloc((size_t)E * 8);
  int2*     csr_ef   = (int2*)alloc((size_t)E * 8);
  (void)ws_size; (void)n_in; (void)out_size;

  auto rz_part = [&](int it) { return rzrr + (size_t)(2 * it) * KB; };
  auto rr_part = [&](int it) { return rzrr + (size_t)(2 * it + 1) * KB; };
  auto pap_part = [&](int it) { return papp + (size_t)it * KB; };

  const int gridE = (E + TPB - 1) / TPB;
  const int gridN = (N + TPB - 1) / TPB;
  const int nbScan = (N + 1023) / 1024;  // <= 512

  hipMemsetAsync(base, 0, zero_bytes, stream);

  hist<<<gridE, TPB, 0, stream>>>(ei, cnt, rank, E);

  scan_blocks<<<nbScan, TPB, 0, stream>>>(cnt, offs, btot, N);
  scan_totals<<<1, 512, 0, stream>>>(btot, nbScan);
  scan_add<<<gridN, TPB, 0, stream>>>(offs, btot, N, (unsigned)E);

  scatter_edges<<<gridE, TPB, 0, stream>>>(ei, u_hat, fn, fa, fd, rank, offs,
                                           csr_sw, csr_ef, E);

  node_setup<<<KB, TPB, 0, stream>>>(csr_sw, csr_ef, offs, cv, diag,
                                     rvec, pvec, phi, minv,
                                     rz_part(0), rr_part(0), N);

  for (int it = 0; it < CG_ITERS; it++) {
    matvec<<<KB, TPB, 0, stream>>>(pvec, diag, offs, csr_sw, ap,
                                   pap_part(it), N);
    cg_update<<<KB, TPB, 0, stream>>>(phi, rvec, pvec, ap, minv,
                                      pap_part(it), rz_part(it), rr_part(it),
                                      rz_part(it + 1), rr_part(it + 1), N);
    if (it < CG_ITERS - 1) {
      p_update<<<KB, TPB, 0, stream>>>(pvec, rvec, minv,
                                       rz_part(it + 1), rz_part(it),
                                       rr_part(it), N);
    }
  }

  finalize<<<KB, TPB, 0, stream>>>(u_hat, cv, phi, offs, csr_sw, csr_ef,
                                   fn, out, N);
}

// Round 5
// 2515.982 us; speedup vs baseline: 4.2016x; 1.0455x over previous
//
#include <hip/hip_runtime.h>

// PressureProjection on MI355X — round 5.
// R4 finding: scatter was write-granule bound (FETCH 1.23GB from write-allocate
// of random 8B stores). This round replaces hist+rank+scatter with a coarse
// bucket sort (bucket = dst>>8, 256 nodes/bucket):
//   bucket_hist  : LDS histogram -> count matrix mat[b][chunk]
//   scan         : exclusive scan of mat (NS = NB*256 entries)
//   bucket_place : recompute w/flux, place edges via LDS rank counters into
//                  bucket-contiguous regions (writes ~16-edge runs, no atomics
//                  on global). Payload A1 = (dstlocal<<19|src, w) 8B;
//                  A2 = flux 4B; A3 = eid 4B.
// No per-row CSR: matvec/node_setup/finalize are one-block-per-bucket with
// 256 LDS accumulators (order within a row is irrelevant for sums).
// No memset: every workspace array is fully written before any read.

#define TPB 256
#define TPB_A 1024
#define KB 2048          // grid for CG vector kernels & partial arrays
#define NBLK 256         // chunks for bucket sort
#define MAXNB 2048       // max coarse buckets (N <= 524288)
#define CG_ITERS 20
#define TOL2 1e-8f       // (CG_TOL=1e-4)^2

struct Sum3 { float a, b, c; };

// block-wide sums of three arrays of length n, broadcast to all threads
__device__ inline Sum3 block_sum3_bcast(const float* __restrict__ A,
                                        const float* __restrict__ B,
                                        const float* __restrict__ C, int n) {
  float va = 0.f, vb = 0.f, vc = 0.f;
  for (int k = threadIdx.x; k < n; k += TPB) { va += A[k]; vb += B[k]; vc += C[k]; }
#pragma unroll
  for (int o = 32; o; o >>= 1) {
    va += __shfl_down(va, o, 64);
    vb += __shfl_down(vb, o, 64);
    vc += __shfl_down(vc, o, 64);
  }
  __shared__ float sa[TPB / 64], sb[TPB / 64], sc[TPB / 64], bc[3];
  int lane = threadIdx.x & 63, wid = threadIdx.x >> 6;
  if (lane == 0) { sa[wid] = va; sb[wid] = vb; sc[wid] = vc; }
  __syncthreads();
  if (threadIdx.x == 0) {
    float ta = 0.f, tb = 0.f, tc = 0.f;
#pragma unroll
    for (int k = 0; k < TPB / 64; k++) { ta += sa[k]; tb += sb[k]; tc += sc[k]; }
    bc[0] = ta; bc[1] = tb; bc[2] = tc;
  }
  __syncthreads();
  Sum3 r{bc[0], bc[1], bc[2]};
  __syncthreads();
  return r;
}

__device__ inline void block_reduce1_store(float v1, float* d1) {
#pragma unroll
  for (int o = 32; o; o >>= 1) v1 += __shfl_down(v1, o, 64);
  __shared__ float s1[TPB / 64];
  int lane = threadIdx.x & 63, wid = threadIdx.x >> 6;
  if (lane == 0) s1[wid] = v1;
  __syncthreads();
  if (threadIdx.x == 0) {
    float t1 = 0.f;
#pragma unroll
    for (int k = 0; k < TPB / 64; k++) t1 += s1[k];
    *d1 = t1;
  }
}

__device__ inline void block_reduce2_store(float v1, float v2, float* d1, float* d2) {
#pragma unroll
  for (int o = 32; o; o >>= 1) {
    v1 += __shfl_down(v1, o, 64);
    v2 += __shfl_down(v2, o, 64);
  }
  __shared__ float s1[TPB / 64], s2[TPB / 64];
  int lane = threadIdx.x & 63, wid = threadIdx.x >> 6;
  if (lane == 0) { s1[wid] = v1; s2[wid] = v2; }
  __syncthreads();
  if (threadIdx.x == 0) {
    float t1 = 0.f, t2 = 0.f;
#pragma unroll
    for (int k = 0; k < TPB / 64; k++) { t1 += s1[k]; t2 += s2[k]; }
    *d1 = t1;
    *d2 = t2;
  }
}

// ---- pass A0: per-chunk LDS histogram of coarse buckets ----
__global__ __launch_bounds__(TPB_A) void bucket_hist(
    const int* __restrict__ ei, unsigned* __restrict__ mat,
    int E, int NB, int chunk) {
  __shared__ unsigned cntL[MAXNB];
  for (int i = threadIdx.x; i < NB; i += TPB_A) cntL[i] = 0;
  __syncthreads();
  int blk = blockIdx.x;
  int e0 = blk * chunk, e1 = min(E, e0 + chunk);
  for (int e = e0 + threadIdx.x; e < e1; e += TPB_A)
    atomicAdd(&cntL[((unsigned)ei[E + e]) >> 8], 1u);
  __syncthreads();
  for (int b = threadIdx.x; b < NB; b += TPB_A)
    mat[(size_t)b * NBLK + blk] = cntL[b];
}

// ---- scan (1024 elems / block) ----
__global__ __launch_bounds__(TPB) void scan_blocks(
    const unsigned* __restrict__ cnt, unsigned* __restrict__ offs,
    unsigned* __restrict__ btot, int n) {
  __shared__ unsigned sd[TPB];
  int t = threadIdx.x;
  int base = blockIdx.x * 1024 + t * 4;
  unsigned v0 = 0, v1 = 0, v2 = 0, v3 = 0;
  if (base + 0 < n) v0 = cnt[base + 0];
  if (base + 1 < n) v1 = cnt[base + 1];
  if (base + 2 < n) v2 = cnt[base + 2];
  if (base + 3 < n) v3 = cnt[base + 3];
  unsigned local = v0 + v1 + v2 + v3;
  sd[t] = local;
  __syncthreads();
  for (int o = 1; o < TPB; o <<= 1) {
    unsigned x = (t >= o) ? sd[t - o] : 0u;
    __syncthreads();
    sd[t] += x;
    __syncthreads();
  }
  unsigned excl = sd[t] - local;
  if (base + 0 < n) offs[base + 0] = excl; excl += v0;
  if (base + 1 < n) offs[base + 1] = excl; excl += v1;
  if (base + 2 < n) offs[base + 2] = excl; excl += v2;
  if (base + 3 < n) offs[base + 3] = excl;
  if (t == TPB - 1) btot[blockIdx.x] = sd[TPB - 1];
}

__global__ __launch_bounds__(512) void scan_totals(unsigned* __restrict__ btot, int nb) {
  __shared__ unsigned sd[512];
  int t = threadIdx.x;
  unsigned v = (t < nb) ? btot[t] : 0u;
  sd[t] = v;
  __syncthreads();
  for (int o = 1; o < 512; o <<= 1) {
    unsigned x = (t >= o) ? sd[t - o] : 0u;
    __syncthreads();
    sd[t] += x;
    __syncthreads();
  }
  if (t < nb) btot[t] = sd[t] - v;  // exclusive
}

__global__ __launch_bounds__(TPB) void scan_add(
    unsigned* __restrict__ offs, const unsigned* __restrict__ btot,
    int n, unsigned total) {
  int i = blockIdx.x * TPB + threadIdx.x;
  if (i < n) offs[i] += btot[i >> 10];
  if (i == 0) offs[n] = total;
}

// ---- pass A1: compute w/flux, place edges into bucket regions ----
__global__ __launch_bounds__(TPB_A) void bucket_place(
    const int* __restrict__ ei, const float* __restrict__ u_hat,
    const float* __restrict__ fn, const float* __restrict__ fa,
    const float* __restrict__ fd, const unsigned* __restrict__ offs,
    unsigned long long* __restrict__ A1, float* __restrict__ A2flux,
    int* __restrict__ A3eid, int E, int NB, int chunk) {
  __shared__ unsigned cntL[MAXNB];
  __shared__ unsigned offL[MAXNB];
  int blk = blockIdx.x;
  for (int i = threadIdx.x; i < NB; i += TPB_A) {
    cntL[i] = 0;
    offL[i] = offs[(size_t)i * NBLK + blk];
  }
  __syncthreads();
  int e0 = blk * chunk, e1 = min(E, e0 + chunk);
  for (int e = e0 + threadIdx.x; e < e1; e += TPB_A) {
    int s = ei[e], d = ei[E + e];
    float area = fa[e];
    float w = area / fmaxf(fd[e], 1e-8f);
    float ux = 0.5f * (u_hat[3 * s]     + u_hat[3 * d]);
    float uy = 0.5f * (u_hat[3 * s + 1] + u_hat[3 * d + 1]);
    float uz = 0.5f * (u_hat[3 * s + 2] + u_hat[3 * d + 2]);
    float flux = (ux * fn[3 * e] + uy * fn[3 * e + 1] + uz * fn[3 * e + 2]) * area;
    unsigned b = ((unsigned)d) >> 8;
    unsigned dl = ((unsigned)d) & 255u;
    unsigned r = atomicAdd(&cntL[b], 1u);
    unsigned pos = offL[b] + r;
    unsigned hi = (dl << 19) | (unsigned)s;
    A1[pos] = ((unsigned long long)hi << 32) | (unsigned long long)__float_as_uint(w);
    A2flux[pos] = flux;
    A3eid[pos] = e;
  }
}

// ---- CG setup: per-bucket LDS sums of w and flux ----
__global__ __launch_bounds__(TPB) void node_setup(
    const unsigned long long* __restrict__ A1, const float* __restrict__ A2flux,
    const unsigned* __restrict__ offs, const float* __restrict__ cv,
    float* __restrict__ diag, float* __restrict__ r, float* __restrict__ p,
    float* __restrict__ phi, float* __restrict__ minv,
    float* __restrict__ rz_part, float* __restrict__ rr_part, int N, int NB) {
  __shared__ float wacc[256], facc[256];
  int b = blockIdx.x;
  float rzv = 0.f, rrv = 0.f;
  if (b < NB) {
    wacc[threadIdx.x] = 0.f;
    facc[threadIdx.x] = 0.f;
    __syncthreads();
    unsigned jb = offs[(size_t)b * NBLK], je = offs[(size_t)(b + 1) * NBLK];
    for (unsigned j = jb + threadIdx.x; j < je; j += TPB) {
      unsigned long long v = A1[j];
      unsigned hi = (unsigned)(v >> 32);
      float w = __uint_as_float((unsigned)v);
      atomicAdd(&wacc[hi >> 19], w);
      atomicAdd(&facc[hi >> 19], A2flux[j]);
    }
    __syncthreads();
    int node = (b << 8) + threadIdx.x;
    if (node < N) {
      float wsum = wacc[threadIdx.x];
      float vol = fmaxf(cv[node], 1e-12f);
      float bval = facc[threadIdx.x] / vol;
      float mi = 1.0f / fmaxf(wsum, 1e-8f);
      diag[node] = wsum;
      minv[node] = mi;
      r[node] = bval;
      phi[node] = 0.f;
      float pi = mi * bval;
      p[node] = pi;
      rzv = bval * pi;
      rrv = bval * bval;
    }
  }
  block_reduce2_store(rzv, rrv, &rz_part[blockIdx.x], &rr_part[blockIdx.x]);
}

// ---- matvec: per-bucket LDS accumulate of w*p[src] ----
__global__ __launch_bounds__(TPB) void matvec(
    const float* __restrict__ p, const float* __restrict__ diag,
    const unsigned* __restrict__ offs, const unsigned long long* __restrict__ A1,
    float* __restrict__ ap, float* __restrict__ pap_part, int N, int NB) {
  __shared__ float acc[256];
  int b = blockIdx.x;
  float contrib = 0.f;
  if (b < NB) {
    acc[threadIdx.x] = 0.f;
    __syncthreads();
    unsigned jb = offs[(size_t)b * NBLK], je = offs[(size_t)(b + 1) * NBLK];
    for (unsigned j = jb + threadIdx.x; j < je; j += TPB) {
      unsigned long long v = A1[j];
      unsigned hi = (unsigned)(v >> 32);
      float w = __uint_as_float((unsigned)v);
      atomicAdd(&acc[hi >> 19], w * p[hi & 0x7FFFFu]);
    }
    __syncthreads();
    int node = (b << 8) + threadIdx.x;
    if (node < N) {
      float pi = p[node];
      float api = diag[node] * pi - acc[threadIdx.x];
      ap[node] = api;
      contrib = pi * api;
    }
  }
  block_reduce1_store(contrib, &pap_part[blockIdx.x]);
}

// ---- gated phi/r update; emits rz/rr partials for next iter ----
__global__ __launch_bounds__(TPB) void cg_update(
    float* __restrict__ phi, float* __restrict__ r, const float* __restrict__ p,
    const float* __restrict__ ap, const float* __restrict__ minv,
    const float* __restrict__ pap_it, const float* __restrict__ rz_it,
    const float* __restrict__ rr_it, float* __restrict__ rz_next,
    float* __restrict__ rr_next, int N) {
  Sum3 s = block_sum3_bcast(pap_it, rz_it, rr_it, KB);
  bool act = (s.c >= TOL2);
  float alpha = s.b / (s.a + 1e-12f);
  float rzacc = 0.f, rracc = 0.f;
  for (int i = blockIdx.x * TPB + threadIdx.x; i < N; i += KB * TPB) {
    float ri = r[i];
    if (act) {
      phi[i] += alpha * p[i];
      ri -= alpha * ap[i];
      r[i] = ri;
    }
    float zi = minv[i] * ri;
    rzacc += ri * zi;
    rracc += ri * ri;
  }
  block_reduce2_store(rzacc, rracc, &rz_next[blockIdx.x], &rr_next[blockIdx.x]);
}

// ---- gated p = z + beta*p ----
__global__ __launch_bounds__(TPB) void p_update(
    float* __restrict__ p, const float* __restrict__ r,
    const float* __restrict__ minv, const float* __restrict__ rz_next,
    const float* __restrict__ rz_it, const float* __restrict__ rr_it, int N) {
  Sum3 s = block_sum3_bcast(rz_next, rz_it, rr_it, KB);
  if (s.c < TOL2) return;  // frozen: p unchanged
  float beta = s.a / (s.b + 1e-12f);
  for (int i = blockIdx.x * TPB + threadIdx.x; i < N; i += KB * TPB) {
    p[i] = minv[i] * r[i] + beta * p[i];
  }
}

// ---- pressure correction + output: per-bucket LDS grad accumulate ----
__global__ __launch_bounds__(TPB) void finalize(
    const float* __restrict__ u_hat, const float* __restrict__ cv,
    const float* __restrict__ phi, const unsigned* __restrict__ offs,
    const unsigned long long* __restrict__ A1, const int* __restrict__ A3eid,
    const float* __restrict__ fn, float* __restrict__ out, int N, int NB) {
  __shared__ float gxa[256], gya[256], gza[256];
  int b = blockIdx.x;
  if (b >= NB) return;
  gxa[threadIdx.x] = 0.f;
  gya[threadIdx.x] = 0.f;
  gza[threadIdx.x] = 0.f;
  __syncthreads();
  unsigned jb = offs[(size_t)b * NBLK], je = offs[(size_t)(b + 1) * NBLK];
  for (unsigned j = jb + threadIdx.x; j < je; j += TPB) {
    unsigned long long v = A1[j];
    unsigned hi = (unsigned)(v >> 32);
    float w = __uint_as_float((unsigned)v);
    float t = w * phi[hi & 0x7FFFFu];
    int e = A3eid[j];
    int dl = hi >> 19;
    atomicAdd(&gxa[dl], t * fn[3 * e]);
    atomicAdd(&gya[dl], t * fn[3 * e + 1]);
    atomicAdd(&gza[dl], t * fn[3 * e + 2]);
  }
  __syncthreads();
  int node = (b << 8) + threadIdx.x;
  if (node < N) {
    float iv = 1.0f / fmaxf(cv[node], 1e-12f);
    out[3 * node]     = u_hat[3 * node]     - gxa[threadIdx.x] * iv;
    out[3 * node + 1] = u_hat[3 * node + 1] - gya[threadIdx.x] * iv;
    out[3 * node + 2] = u_hat[3 * node + 2] - gza[threadIdx.x] * iv;
    out[3 * N + node] = phi[node];
  }
}

extern "C" void kernel_launch(void* const* d_in, const int* in_sizes, int n_in,
                              void* d_out, int out_size, void* d_ws, size_t ws_size,
                              hipStream_t stream) {
  const float* u_hat = (const float*)d_in[0];
  const int*   ei    = (const int*)d_in[1];
  const float* fn    = (const float*)d_in[2];
  const float* fa    = (const float*)d_in[3];
  const float* fd    = (const float*)d_in[4];
  const float* cv    = (const float*)d_in[5];
  float* out = (float*)d_out;

  const int N = in_sizes[0] / 3;   // 500,000
  const int E = in_sizes[1] / 2;   // 8,000,000
  const int NB = (N + 255) >> 8;   // coarse buckets (1954)
  const int NS = NB * NBLK;        // scan length (500,224)
  const int chunk = (E + NBLK - 1) / NBLK;

  // ---- workspace bump allocator (256B aligned); ~145 MB ----
  char* base = (char*)d_ws;
  size_t off = 0;
  auto alloc = [&](size_t bytes) -> void* {
    void* ptr = base + off;
    off = (off + bytes + 255) & ~size_t(255);
    return ptr;
  };
  unsigned* mat   = (unsigned*)alloc((size_t)NS * 4);
  unsigned* offs  = (unsigned*)alloc((size_t)(NS + 1) * 4);
  unsigned* btot  = (unsigned*)alloc(512 * 4);
  float*    diag  = (float*)alloc((size_t)N * 4);
  float*    minv  = (float*)alloc((size_t)N * 4);
  float*    phi   = (float*)alloc((size_t)N * 4);
  float*    rvec  = (float*)alloc((size_t)N * 4);
  float*    pvec  = (float*)alloc((size_t)N * 4);
  float*    ap    = (float*)alloc((size_t)N * 4);
  float*    rzrr  = (float*)alloc((size_t)(2 * (CG_ITERS + 1)) * KB * 4);
  float*    papp  = (float*)alloc((size_t)CG_ITERS * KB * 4);
  unsigned long long* A1 = (unsigned long long*)alloc((size_t)E * 8);
  float*    A2flux = (float*)alloc((size_t)E * 4);
  int*      A3eid  = (int*)alloc((size_t)E * 4);
  (void)ws_size; (void)n_in; (void)out_size;

  auto rz_part = [&](int it) { return rzrr + (size_t)(2 * it) * KB; };
  auto rr_part = [&](int it) { return rzrr + (size_t)(2 * it + 1) * KB; };
  auto pap_part = [&](int it) { return papp + (size_t)it * KB; };

  const int nbScan = (NS + 1023) / 1024;          // 489 <= 512
  const int gridScanAdd = (NS + TPB - 1) / TPB;

  bucket_hist<<<NBLK, TPB_A, 0, stream>>>(ei, mat, E, NB, chunk);

  scan_blocks<<<nbScan, TPB, 0, stream>>>(mat, offs, btot, NS);
  scan_totals<<<1, 512, 0, stream>>>(btot, nbScan);
  scan_add<<<gridScanAdd, TPB, 0, stream>>>(offs, btot, NS, (unsigned)E);

  bucket_place<<<NBLK, TPB_A, 0, stream>>>(ei, u_hat, fn, fa, fd, offs,
                                           A1, A2flux, A3eid, E, NB, chunk);

  node_setup<<<KB, TPB, 0, stream>>>(A1, A2flux, offs, cv, diag,
                                     rvec, pvec, phi, minv,
                                     rz_part(0), rr_part(0), N, NB);

  for (int it = 0; it < CG_ITERS; it++) {
    matvec<<<KB, TPB, 0, stream>>>(pvec, diag, offs, A1, ap,
                                   pap_part(it), N, NB);
    cg_update<<<KB, TPB, 0, stream>>>(phi, rvec, pvec, ap, minv,
                                      pap_part(it), rz_part(it), rr_part(it),
                                      rz_part(it + 1), rr_part(it + 1), N);
    if (it < CG_ITERS - 1) {
      p_update<<<KB, TPB, 0, stream>>>(pvec, rvec, minv,
                                       rz_part(it + 1), rz_part(it),
                                       rr_part(it), N);
    }
  }

  finalize<<<NB, TPB, 0, stream>>>(u_hat, cv, phi, offs, A1, A3eid,
                                   fn, out, N, NB);
}

// Round 6
// 2304.202 us; speedup vs baseline: 4.5878x; 1.0919x over previous
//
#include <hip/hip_runtime.h>

// PressureProjection on MI355X — round 6.
// R5 finding: bucket_place still write-granule bound (3 payload arrays x 1954
// buckets of ~16-edge runs -> ~12MB of partial lines per XCD >> 4MB L2 ->
// eviction before fill). This round:
//  * bucket = dst>>9 (512 nodes/bucket, NB=977) -> ~32-edge runs
//  * TWO payload arrays: A1=(dl<<19|src, w) 8B hot stream for matvec;
//    A2=(eid, flux) 8B cold (node_setup reads flux, finalize reads eid)
//    -> active partial-line footprint ~4MB/XCD, fits L2
//  * bucket kernels use 512 threads (1 thread per node in bucket)
// No memset: every workspace array fully written before read.

#define TPB 256
#define TPB_B 512        // bucket kernels (512 nodes per bucket)
#define TPB_A 1024
#define KB 2048          // grid for CG vector kernels & partial arrays
#define NBLK 256         // chunks for bucket sort
#define MAXNB 1024       // max coarse buckets (N <= 524288)
#define CG_ITERS 20
#define TOL2 1e-8f       // (CG_TOL=1e-4)^2

struct Sum3 { float a, b, c; };

// block-wide sums of three arrays of length n, broadcast (TPB threads)
__device__ inline Sum3 block_sum3_bcast(const float* __restrict__ A,
                                        const float* __restrict__ B,
                                        const float* __restrict__ C, int n) {
  float va = 0.f, vb = 0.f, vc = 0.f;
  for (int k = threadIdx.x; k < n; k += TPB) { va += A[k]; vb += B[k]; vc += C[k]; }
#pragma unroll
  for (int o = 32; o; o >>= 1) {
    va += __shfl_down(va, o, 64);
    vb += __shfl_down(vb, o, 64);
    vc += __shfl_down(vc, o, 64);
  }
  __shared__ float sa[TPB / 64], sb[TPB / 64], sc[TPB / 64], bc[3];
  int lane = threadIdx.x & 63, wid = threadIdx.x >> 6;
  if (lane == 0) { sa[wid] = va; sb[wid] = vb; sc[wid] = vc; }
  __syncthreads();
  if (threadIdx.x == 0) {
    float ta = 0.f, tb = 0.f, tc = 0.f;
#pragma unroll
    for (int k = 0; k < TPB / 64; k++) { ta += sa[k]; tb += sb[k]; tc += sc[k]; }
    bc[0] = ta; bc[1] = tb; bc[2] = tc;
  }
  __syncthreads();
  Sum3 r{bc[0], bc[1], bc[2]};
  __syncthreads();
  return r;
}

template <int BS>
__device__ inline void block_reduce1_store(float v1, float* d1) {
#pragma unroll
  for (int o = 32; o; o >>= 1) v1 += __shfl_down(v1, o, 64);
  __shared__ float s1[BS / 64];
  int lane = threadIdx.x & 63, wid = threadIdx.x >> 6;
  if (lane == 0) s1[wid] = v1;
  __syncthreads();
  if (threadIdx.x == 0) {
    float t1 = 0.f;
#pragma unroll
    for (int k = 0; k < BS / 64; k++) t1 += s1[k];
    *d1 = t1;
  }
}

template <int BS>
__device__ inline void block_reduce2_store(float v1, float v2, float* d1, float* d2) {
#pragma unroll
  for (int o = 32; o; o >>= 1) {
    v1 += __shfl_down(v1, o, 64);
    v2 += __shfl_down(v2, o, 64);
  }
  __shared__ float s1[BS / 64], s2[BS / 64];
  int lane = threadIdx.x & 63, wid = threadIdx.x >> 6;
  if (lane == 0) { s1[wid] = v1; s2[wid] = v2; }
  __syncthreads();
  if (threadIdx.x == 0) {
    float t1 = 0.f, t2 = 0.f;
#pragma unroll
    for (int k = 0; k < BS / 64; k++) { t1 += s1[k]; t2 += s2[k]; }
    *d1 = t1;
    *d2 = t2;
  }
}

// ---- pass A0: per-chunk LDS histogram of coarse buckets ----
__global__ __launch_bounds__(TPB_A) void bucket_hist(
    const int* __restrict__ ei, unsigned* __restrict__ mat,
    int E, int NB, int chunk) {
  __shared__ unsigned cntL[MAXNB];
  for (int i = threadIdx.x; i < NB; i += TPB_A) cntL[i] = 0;
  __syncthreads();
  int blk = blockIdx.x;
  int e0 = blk * chunk, e1 = min(E, e0 + chunk);
  for (int e = e0 + threadIdx.x; e < e1; e += TPB_A)
    atomicAdd(&cntL[((unsigned)ei[E + e]) >> 9], 1u);
  __syncthreads();
  for (int b = threadIdx.x; b < NB; b += TPB_A)
    mat[(size_t)b * NBLK + blk] = cntL[b];
}

// ---- scan (1024 elems / block) ----
__global__ __launch_bounds__(TPB) void scan_blocks(
    const unsigned* __restrict__ cnt, unsigned* __restrict__ offs,
    unsigned* __restrict__ btot, int n) {
  __shared__ unsigned sd[TPB];
  int t = threadIdx.x;
  int base = blockIdx.x * 1024 + t * 4;
  unsigned v0 = 0, v1 = 0, v2 = 0, v3 = 0;
  if (base + 0 < n) v0 = cnt[base + 0];
  if (base + 1 < n) v1 = cnt[base + 1];
  if (base + 2 < n) v2 = cnt[base + 2];
  if (base + 3 < n) v3 = cnt[base + 3];
  unsigned local = v0 + v1 + v2 + v3;
  sd[t] = local;
  __syncthreads();
  for (int o = 1; o < TPB; o <<= 1) {
    unsigned x = (t >= o) ? sd[t - o] : 0u;
    __syncthreads();
    sd[t] += x;
    __syncthreads();
  }
  unsigned excl = sd[t] - local;
  if (base + 0 < n) offs[base + 0] = excl; excl += v0;
  if (base + 1 < n) offs[base + 1] = excl; excl += v1;
  if (base + 2 < n) offs[base + 2] = excl; excl += v2;
  if (base + 3 < n) offs[base + 3] = excl;
  if (t == TPB - 1) btot[blockIdx.x] = sd[TPB - 1];
}

__global__ __launch_bounds__(512) void scan_totals(unsigned* __restrict__ btot, int nb) {
  __shared__ unsigned sd[512];
  int t = threadIdx.x;
  unsigned v = (t < nb) ? btot[t] : 0u;
  sd[t] = v;
  __syncthreads();
  for (int o = 1; o < 512; o <<= 1) {
    unsigned x = (t >= o) ? sd[t - o] : 0u;
    __syncthreads();
    sd[t] += x;
    __syncthreads();
  }
  if (t < nb) btot[t] = sd[t] - v;  // exclusive
}

__global__ __launch_bounds__(TPB) void scan_add(
    unsigned* __restrict__ offs, const unsigned* __restrict__ btot,
    int n, unsigned total) {
  int i = blockIdx.x * TPB + threadIdx.x;
  if (i < n) offs[i] += btot[i >> 10];
  if (i == 0) offs[n] = total;
}

// ---- pass A1: compute w/flux, place edges into bucket regions ----
__global__ __launch_bounds__(TPB_A) void bucket_place(
    const int* __restrict__ ei, const float* __restrict__ u_hat,
    const float* __restrict__ fn, const float* __restrict__ fa,
    const float* __restrict__ fd, const unsigned* __restrict__ offs,
    unsigned long long* __restrict__ A1, int2* __restrict__ A2,
    int E, int NB, int chunk) {
  __shared__ unsigned cntL[MAXNB];
  __shared__ unsigned offL[MAXNB];
  int blk = blockIdx.x;
  for (int i = threadIdx.x; i < NB; i += TPB_A) {
    cntL[i] = 0;
    offL[i] = offs[(size_t)i * NBLK + blk];
  }
  __syncthreads();
  int e0 = blk * chunk, e1 = min(E, e0 + chunk);
  for (int e = e0 + threadIdx.x; e < e1; e += TPB_A) {
    int s = ei[e], d = ei[E + e];
    float area = fa[e];
    float w = area / fmaxf(fd[e], 1e-8f);
    float ux = 0.5f * (u_hat[3 * s]     + u_hat[3 * d]);
    float uy = 0.5f * (u_hat[3 * s + 1] + u_hat[3 * d + 1]);
    float uz = 0.5f * (u_hat[3 * s + 2] + u_hat[3 * d + 2]);
    float flux = (ux * fn[3 * e] + uy * fn[3 * e + 1] + uz * fn[3 * e + 2]) * area;
    unsigned b = ((unsigned)d) >> 9;
    unsigned dl = ((unsigned)d) & 511u;
    unsigned r = atomicAdd(&cntL[b], 1u);
    unsigned pos = offL[b] + r;
    unsigned hi = (dl << 19) | (unsigned)s;
    A1[pos] = ((unsigned long long)hi << 32) | (unsigned long long)__float_as_uint(w);
    A2[pos] = make_int2(e, __float_as_int(flux));
  }
}

// ---- CG setup: per-bucket LDS sums of w and flux ----
__global__ __launch_bounds__(TPB_B) void node_setup(
    const unsigned long long* __restrict__ A1, const int2* __restrict__ A2,
    const unsigned* __restrict__ offs, const float* __restrict__ cv,
    float* __restrict__ diag, float* __restrict__ r, float* __restrict__ p,
    float* __restrict__ phi, float* __restrict__ minv,
    float* __restrict__ rz_part, float* __restrict__ rr_part, int N, int NB) {
  __shared__ float wacc[TPB_B], facc[TPB_B];
  int b = blockIdx.x;
  float rzv = 0.f, rrv = 0.f;
  if (b < NB) {
    wacc[threadIdx.x] = 0.f;
    facc[threadIdx.x] = 0.f;
    __syncthreads();
    unsigned jb = offs[(size_t)b * NBLK], je = offs[(size_t)(b + 1) * NBLK];
    for (unsigned j = jb + threadIdx.x; j < je; j += TPB_B) {
      unsigned long long v = A1[j];
      unsigned hi = (unsigned)(v >> 32);
      float w = __uint_as_float((unsigned)v);
      atomicAdd(&wacc[hi >> 19], w);
      atomicAdd(&facc[hi >> 19], __int_as_float(A2[j].y));
    }
    __syncthreads();
    int node = (b << 9) + threadIdx.x;
    if (node < N) {
      float wsum = wacc[threadIdx.x];
      float vol = fmaxf(cv[node], 1e-12f);
      float bval = facc[threadIdx.x] / vol;
      float mi = 1.0f / fmaxf(wsum, 1e-8f);
      diag[node] = wsum;
      minv[node] = mi;
      r[node] = bval;
      phi[node] = 0.f;
      float pi = mi * bval;
      p[node] = pi;
      rzv = bval * pi;
      rrv = bval * bval;
    }
  }
  block_reduce2_store<TPB_B>(rzv, rrv, &rz_part[blockIdx.x], &rr_part[blockIdx.x]);
}

// ---- matvec: per-bucket LDS accumulate of w*p[src] ----
__global__ __launch_bounds__(TPB_B) void matvec(
    const float* __restrict__ p, const float* __restrict__ diag,
    const unsigned* __restrict__ offs, const unsigned long long* __restrict__ A1,
    float* __restrict__ ap, float* __restrict__ pap_part, int N, int NB) {
  __shared__ float acc[TPB_B];
  int b = blockIdx.x;
  float contrib = 0.f;
  if (b < NB) {
    acc[threadIdx.x] = 0.f;
    __syncthreads();
    unsigned jb = offs[(size_t)b * NBLK], je = offs[(size_t)(b + 1) * NBLK];
    for (unsigned j = jb + threadIdx.x; j < je; j += TPB_B) {
      unsigned long long v = A1[j];
      unsigned hi = (unsigned)(v >> 32);
      float w = __uint_as_float((unsigned)v);
      atomicAdd(&acc[hi >> 19], w * p[hi & 0x7FFFFu]);
    }
    __syncthreads();
    int node = (b << 9) + threadIdx.x;
    if (node < N) {
      float pi = p[node];
      float api = diag[node] * pi - acc[threadIdx.x];
      ap[node] = api;
      contrib = pi * api;
    }
  }
  block_reduce1_store<TPB_B>(contrib, &pap_part[blockIdx.x]);
}

// ---- gated phi/r update; emits rz/rr partials for next iter ----
__global__ __launch_bounds__(TPB) void cg_update(
    float* __restrict__ phi, float* __restrict__ r, const float* __restrict__ p,
    const float* __restrict__ ap, const float* __restrict__ minv,
    const float* __restrict__ pap_it, const float* __restrict__ rz_it,
    const float* __restrict__ rr_it, float* __restrict__ rz_next,
    float* __restrict__ rr_next, int N) {
  Sum3 s = block_sum3_bcast(pap_it, rz_it, rr_it, KB);
  bool act = (s.c >= TOL2);
  float alpha = s.b / (s.a + 1e-12f);
  float rzacc = 0.f, rracc = 0.f;
  for (int i = blockIdx.x * TPB + threadIdx.x; i < N; i += KB * TPB) {
    float ri = r[i];
    if (act) {
      phi[i] += alpha * p[i];
      ri -= alpha * ap[i];
      r[i] = ri;
    }
    float zi = minv[i] * ri;
    rzacc += ri * zi;
    rracc += ri * ri;
  }
  block_reduce2_store<TPB>(rzacc, rracc, &rz_next[blockIdx.x], &rr_next[blockIdx.x]);
}

// ---- gated p = z + beta*p ----
__global__ __launch_bounds__(TPB) void p_update(
    float* __restrict__ p, const float* __restrict__ r,
    const float* __restrict__ minv, const float* __restrict__ rz_next,
    const float* __restrict__ rz_it, const float* __restrict__ rr_it, int N) {
  Sum3 s = block_sum3_bcast(rz_next, rz_it, rr_it, KB);
  if (s.c < TOL2) return;  // frozen: p unchanged
  float beta = s.a / (s.b + 1e-12f);
  for (int i = blockIdx.x * TPB + threadIdx.x; i < N; i += KB * TPB) {
    p[i] = minv[i] * r[i] + beta * p[i];
  }
}

// ---- pressure correction + output: per-bucket LDS grad accumulate ----
__global__ __launch_bounds__(TPB_B) void finalize(
    const float* __restrict__ u_hat, const float* __restrict__ cv,
    const float* __restrict__ phi, const unsigned* __restrict__ offs,
    const unsigned long long* __restrict__ A1, const int2* __restrict__ A2,
    const float* __restrict__ fn, float* __restrict__ out, int N, int NB) {
  __shared__ float gxa[TPB_B], gya[TPB_B], gza[TPB_B];
  int b = blockIdx.x;
  if (b >= NB) return;
  gxa[threadIdx.x] = 0.f;
  gya[threadIdx.x] = 0.f;
  gza[threadIdx.x] = 0.f;
  __syncthreads();
  unsigned jb = offs[(size_t)b * NBLK], je = offs[(size_t)(b + 1) * NBLK];
  for (unsigned j = jb + threadIdx.x; j < je; j += TPB_B) {
    unsigned long long v = A1[j];
    unsigned hi = (unsigned)(v >> 32);
    float w = __uint_as_float((unsigned)v);
    float t = w * phi[hi & 0x7FFFFu];
    int e = A2[j].x;
    int dl = hi >> 19;
    atomicAdd(&gxa[dl], t * fn[3 * e]);
    atomicAdd(&gya[dl], t * fn[3 * e + 1]);
    atomicAdd(&gza[dl], t * fn[3 * e + 2]);
  }
  __syncthreads();
  int node = (b << 9) + threadIdx.x;
  if (node < N) {
    float iv = 1.0f / fmaxf(cv[node], 1e-12f);
    out[3 * node]     = u_hat[3 * node]     - gxa[threadIdx.x] * iv;
    out[3 * node + 1] = u_hat[3 * node + 1] - gya[threadIdx.x] * iv;
    out[3 * node + 2] = u_hat[3 * node + 2] - gza[threadIdx.x] * iv;
    out[3 * N + node] = phi[node];
  }
}

extern "C" void kernel_launch(void* const* d_in, const int* in_sizes, int n_in,
                              void* d_out, int out_size, void* d_ws, size_t ws_size,
                              hipStream_t stream) {
  const float* u_hat = (const float*)d_in[0];
  const int*   ei    = (const int*)d_in[1];
  const float* fn    = (const float*)d_in[2];
  const float* fa    = (const float*)d_in[3];
  const float* fd    = (const float*)d_in[4];
  const float* cv    = (const float*)d_in[5];
  float* out = (float*)d_out;

  const int N = in_sizes[0] / 3;   // 500,000
  const int E = in_sizes[1] / 2;   // 8,000,000
  const int NB = (N + 511) >> 9;   // coarse buckets (977)
  const int NS = NB * NBLK;        // scan length (250,112)
  const int chunk = (E + NBLK - 1) / NBLK;

  // ---- workspace bump allocator (256B aligned); ~145 MB ----
  char* base = (char*)d_ws;
  size_t off = 0;
  auto alloc = [&](size_t bytes) -> void* {
    void* ptr = base + off;
    off = (off + bytes + 255) & ~size_t(255);
    return ptr;
  };
  unsigned* mat   = (unsigned*)alloc((size_t)NS * 4);
  unsigned* offs  = (unsigned*)alloc((size_t)(NS + 1) * 4);
  unsigned* btot  = (unsigned*)alloc(512 * 4);
  float*    diag  = (float*)alloc((size_t)N * 4);
  float*    minv  = (float*)alloc((size_t)N * 4);
  float*    phi   = (float*)alloc((size_t)N * 4);
  float*    rvec  = (float*)alloc((size_t)N * 4);
  float*    pvec  = (float*)alloc((size_t)N * 4);
  float*    ap    = (float*)alloc((size_t)N * 4);
  float*    rzrr  = (float*)alloc((size_t)(2 * (CG_ITERS + 1)) * KB * 4);
  float*    papp  = (float*)alloc((size_t)CG_ITERS * KB * 4);
  unsigned long long* A1 = (unsigned long long*)alloc((size_t)E * 8);
  int2*     A2    = (int2*)alloc((size_t)E * 8);
  (void)ws_size; (void)n_in; (void)out_size;

  auto rz_part = [&](int it) { return rzrr + (size_t)(2 * it) * KB; };
  auto rr_part = [&](int it) { return rzrr + (size_t)(2 * it + 1) * KB; };
  auto pap_part = [&](int it) { return papp + (size_t)it * KB; };

  const int nbScan = (NS + 1023) / 1024;          // 245 <= 512
  const int gridScanAdd = (NS + TPB - 1) / TPB;

  bucket_hist<<<NBLK, TPB_A, 0, stream>>>(ei, mat, E, NB, chunk);

  scan_blocks<<<nbScan, TPB, 0, stream>>>(mat, offs, btot, NS);
  scan_totals<<<1, 512, 0, stream>>>(btot, nbScan);
  scan_add<<<gridScanAdd, TPB, 0, stream>>>(offs, btot, NS, (unsigned)E);

  bucket_place<<<NBLK, TPB_A, 0, stream>>>(ei, u_hat, fn, fa, fd, offs,
                                           A1, A2, E, NB, chunk);

  node_setup<<<KB, TPB_B, 0, stream>>>(A1, A2, offs, cv, diag,
                                       rvec, pvec, phi, minv,
                                       rz_part(0), rr_part(0), N, NB);

  for (int it = 0; it < CG_ITERS; it++) {
    matvec<<<KB, TPB_B, 0, stream>>>(pvec, diag, offs, A1, ap,
                                     pap_part(it), N, NB);
    cg_update<<<KB, TPB, 0, stream>>>(phi, rvec, pvec, ap, minv,
                                      pap_part(it), rz_part(it), rr_part(it),
                                      rz_part(it + 1), rr_part(it + 1), N);
    if (it < CG_ITERS - 1) {
      p_update<<<KB, TPB, 0, stream>>>(pvec, rvec, minv,
                                       rz_part(it + 1), rz_part(it),
                                       rr_part(it), N);
    }
  }

  finalize<<<NB, TPB_B, 0, stream>>>(u_hat, cv, phi, offs, A1, A2,
                                     fn, out, N, NB);
}